// Round 1
// 126.244 us; speedup vs baseline: 1.0181x; 1.0181x over previous
//
#include <hip/hip_runtime.h>
#include <cstdint>

#define BATCHES 8
#define NPTS 2048
#define NF 512
#define KNN 32
#define WAVES 8   // 512-thread block = 8 waves
#define QPW 2     // queries per wave: software pipeline (gather A || dist B)

// grid = 8 batches * 128 chunks = 1024 blocks; batch = blockIdx & 7 (XCD L2 affinity)
// LDS = 32768 (pts4) + 4096 (ckey) + 1024 (sel) = 37888 B -> 4 blocks = 148 KB < 160.
// (512,4): loose reg cap; tight caps scratch-spill db[32] (prev session evidence).

typedef float vfloat4 __attribute__((ext_vector_type(4)));  // native vec for nt-store

__global__ __launch_bounds__(512, 4)
void pointnetpp_knn_maxpool(const float* __restrict__ x,
                            const float* __restrict__ points,
                            float* __restrict__ out) {
    __shared__ __align__(16) float    pts4[NPTS * 4];    // [N][4]: one b128/candidate
    __shared__ __align__(16) uint64_t ckey[WAVES][64];   // candidate keys (fast path)
    __shared__ __align__(16) int      sel[WAVES][KNN];   // fallback emit only

    const int tid  = threadIdx.x;
    const int lane = tid & 63;
    const int w    = tid >> 6;

    const int b     = blockIdx.x & 7;
    const int chunk = blockIdx.x >> 3;

    // ---- stage points[b] into LDS as [N][4] (pad .w) ----
    {
        const float* src = points + (size_t)b * NPTS * 3;
        for (int p = tid; p < NPTS; p += 512) {
            float4* d = (float4*)&pts4[p * 4];
            *d = make_float4(src[p * 3 + 0], src[p * 3 + 1], src[p * 3 + 2], 0.f);
        }
    }
    __syncthreads();

    const uint64_t lmlt = (1ull << lane) - 1ull;
    const float*   xb   = x + (size_t)b * NPTS * NF;

    const int iA = (chunk * WAVES + w) * QPW;   // this wave's queries: iA, iA+1

    uint32_t db[32];   // register-reused across both queries

    auto countLE = [&](uint32_t t) {
        uint32_t c = 0;
        #pragma unroll
        for (int j = 0; j < 32; ++j)
            c += (uint32_t)__builtin_popcountll(__ballot(db[j] <= t));
        return c;
    };

    // exact top-32 select on db[] (bit patterns; float order == uint order, d2 >= 0)
    auto select32 = [&]() -> int {
        // per-lane min of its 32 candidates
        uint32_t lmin = db[0];
        #pragma unroll
        for (int j = 1; j < 32; ++j) lmin = min(lmin, db[j]);

        // ---- bitonic sort64 (ascending) of the 64 lane minima ----
        // rank statistics: the 32nd-smallest lane-min has expected global
        // count ~42 -> usually lands in the [32,64] window in ONE probe.
        uint32_t sm = lmin;
        #pragma unroll
        for (int k = 2; k <= 64; k <<= 1) {
            #pragma unroll
            for (int j = k >> 1; j > 0; j >>= 1) {
                const uint32_t other = (uint32_t)__shfl_xor((int)sm, j);
                const uint32_t mn = min(sm, other);
                const uint32_t mx = max(sm, other);
                sm = (((lane & j) == 0) == ((lane & k) == 0)) ? mn : mx;
            }
        }
        const uint32_t probe = (uint32_t)__builtin_amdgcn_readlane((int)sm, 31);
        const uint32_t hi0   = (uint32_t)__builtin_amdgcn_readlane((int)sm, 63);

        uint32_t thr = 0u, cthr = 0u;
        bool     have = false;
        uint32_t lo = 0u, hi = hi0;   // invariant targets: c(lo)<32, c(hi)>64

        // probe 1: 32nd-smallest lane-min (count(<=probe) >= 32 guaranteed)
        const uint32_t c1 = countLE(probe);
        if (c1 >= KNN && c1 <= 64u) { thr = probe; cthr = c1; have = true; }
        if (!have) {
            // probe 2: wave-max of lane minima (count >= 64 by construction)
            const uint32_t cs = countLE(hi0);
            if (cs <= 64u) { thr = hi0; cthr = cs; have = true; }
            else {
                if (c1 > 64u && probe > 0u) hi = probe;   // tight upper bracket
                while (!have && hi - lo > 1u) {
                    const uint32_t mid = lo + ((hi - lo) >> 1);
                    const uint32_t c   = countLE(mid);
                    if (c >= KNN && c <= 64u) { thr = mid; cthr = c; have = true; break; }
                    if (c > 64u) hi = mid; else lo = mid;
                }
            }
        }

        int selv;   // per-lane: lanes 0..31 hold the 32 selected indices
        if (have) {
            // ---- compact <=64 candidates to LDS as 43-bit keys (d2<<11 | idx) ----
            uint32_t base = 0;
            #pragma unroll
            for (int j = 0; j < 32; ++j) {
                const bool     p = db[j] <= thr;
                const uint64_t m = __ballot(p);
                if (p) {
                    const int slot = (int)base + (int)__popcll(m & lmlt);
                    ckey[w][slot] = (((uint64_t)db[j]) << 11) | (uint64_t)(lane + (j << 6));
                }
                base += (uint32_t)__builtin_popcountll(m);
            }
            uint64_t key = (lane < (int)cthr) ? ckey[w][lane] : ~0ull;

            // ---- wave bitonic sort64 ascending on (d2, idx) ----
            #pragma unroll
            for (int k = 2; k <= 64; k <<= 1) {
                #pragma unroll
                for (int j = k >> 1; j > 0; j >>= 1) {
                    const uint64_t other = __shfl_xor((unsigned long long)key, j);
                    const bool takeMin = (((lane & j) == 0) == ((lane & k) == 0));
                    const uint64_t mn = key < other ? key : other;
                    const uint64_t mx = key < other ? other : key;
                    key = takeMin ? mn : mx;
                }
            }
            selv = (int)(key & 0x7FFull);   // lanes 0..31: exact top-32 (ref tie order)
        } else {
            // ---- exact-tie fallback: T = hi; all <T, then ==T ascending-n ----
            const uint32_t T = hi;
            const int cnt_lt = (int)countLE(lo);   // lo == hi-1 here -> count(<T)
            int base_lt = 0, base_eq = 0;
            #pragma unroll
            for (int j = 0; j < 32; ++j) {
                const bool lt = db[j] < T;
                const bool eq = db[j] == T;
                const uint64_t mlt = __ballot(lt);
                const uint64_t meq = __ballot(eq);
                int slot = -1;
                if (lt)      slot = base_lt + (int)__popcll(mlt & lmlt);
                else if (eq) slot = cnt_lt + base_eq + (int)__popcll(meq & lmlt);
                if (slot >= 0 && slot < KNN) sel[w][slot] = lane + (j << 6);
                base_lt += (int)__popcll(mlt);
                base_eq += (int)__popcll(meq);
            }
            selv = sel[w][lane & (KNN - 1)];
        }
        return selv;
    };

    // ================= query A: distances + select =================
    {
        const float4 qp = *(const float4*)&pts4[iA * 4];
        #pragma unroll
        for (int j = 0; j < 32; ++j) {
            const int n = lane + (j << 6);
            const float4 pp = *(const float4*)&pts4[n * 4];
            const float dx = qp.x - pp.x;
            const float dy = qp.y - pp.y;
            const float dz = qp.z - pp.z;
            db[j] = __float_as_uint(dx * dx + dy * dy + dz * dz);
        }
    }
    const int selvA = select32();

    // ===== fused: gather+maxpool A (VMEM) || distances B (VALU/LDS) =====
    // dist-B ops fill the L2-latency shadow of A's row loads.
    const float4 qpB = *(const float4*)&pts4[(iA + 1) * 4];
    float4 a0 = make_float4(-INFINITY, -INFINITY, -INFINITY, -INFINITY);
    float4 a1 = a0;
    #pragma unroll   // FULL unroll: db[jj] must stay compile-time indexed (regs)
    for (int jj = 0; jj < 32; jj += 2) {
        const int n0 = __builtin_amdgcn_readlane(selvA, jj)     & (NPTS - 1);
        const int n1 = __builtin_amdgcn_readlane(selvA, jj + 1) & (NPTS - 1);
        const float4* r0 = (const float4*)(xb + (size_t)n0 * NF);
        const float4* r1 = (const float4*)(xb + (size_t)n1 * NF);
        const float4 v00 = r0[lane];
        const float4 v01 = r0[lane + 64];
        const float4 v10 = r1[lane];
        const float4 v11 = r1[lane + 64];
        {   // distance pair for query B
            const int n = lane + (jj << 6);
            const float4 p0 = *(const float4*)&pts4[n * 4];
            const float4 p1 = *(const float4*)&pts4[(n + 64) * 4];
            const float dx0 = qpB.x - p0.x, dy0 = qpB.y - p0.y, dz0 = qpB.z - p0.z;
            const float dx1 = qpB.x - p1.x, dy1 = qpB.y - p1.y, dz1 = qpB.z - p1.z;
            db[jj]     = __float_as_uint(dx0 * dx0 + dy0 * dy0 + dz0 * dz0);
            db[jj + 1] = __float_as_uint(dx1 * dx1 + dy1 * dy1 + dz1 * dz1);
        }
        // paired reduction -> v_max3_f32
        a0.x = fmaxf(fmaxf(a0.x, v00.x), v10.x);
        a0.y = fmaxf(fmaxf(a0.y, v00.y), v10.y);
        a0.z = fmaxf(fmaxf(a0.z, v00.z), v10.z);
        a0.w = fmaxf(fmaxf(a0.w, v00.w), v10.w);
        a1.x = fmaxf(fmaxf(a1.x, v01.x), v11.x);
        a1.y = fmaxf(fmaxf(a1.y, v01.y), v11.y);
        a1.z = fmaxf(fmaxf(a1.z, v01.z), v11.z);
        a1.w = fmaxf(fmaxf(a1.w, v01.w), v11.w);
    }
    {
        vfloat4* orow = (vfloat4*)(out + ((size_t)b * NPTS + iA) * NF);
        __builtin_nontemporal_store(vfloat4{a0.x, a0.y, a0.z, a0.w}, &orow[lane]);
        __builtin_nontemporal_store(vfloat4{a1.x, a1.y, a1.z, a1.w}, &orow[lane + 64]);
    }

    // ================= query B: select + gather =================
    const int selvB = select32();
    a0 = make_float4(-INFINITY, -INFINITY, -INFINITY, -INFINITY);
    a1 = a0;
    #pragma unroll 4
    for (int jj = 0; jj < 32; jj += 2) {
        const int n0 = __builtin_amdgcn_readlane(selvB, jj)     & (NPTS - 1);
        const int n1 = __builtin_amdgcn_readlane(selvB, jj + 1) & (NPTS - 1);
        const float4* r0 = (const float4*)(xb + (size_t)n0 * NF);
        const float4* r1 = (const float4*)(xb + (size_t)n1 * NF);
        const float4 v00 = r0[lane];
        const float4 v01 = r0[lane + 64];
        const float4 v10 = r1[lane];
        const float4 v11 = r1[lane + 64];
        a0.x = fmaxf(fmaxf(a0.x, v00.x), v10.x);
        a0.y = fmaxf(fmaxf(a0.y, v00.y), v10.y);
        a0.z = fmaxf(fmaxf(a0.z, v00.z), v10.z);
        a0.w = fmaxf(fmaxf(a0.w, v00.w), v10.w);
        a1.x = fmaxf(fmaxf(a1.x, v01.x), v11.x);
        a1.y = fmaxf(fmaxf(a1.y, v01.y), v11.y);
        a1.z = fmaxf(fmaxf(a1.z, v01.z), v11.z);
        a1.w = fmaxf(fmaxf(a1.w, v01.w), v11.w);
    }
    {
        vfloat4* orow = (vfloat4*)(out + ((size_t)b * NPTS + iA + 1) * NF);
        __builtin_nontemporal_store(vfloat4{a0.x, a0.y, a0.z, a0.w}, &orow[lane]);
        __builtin_nontemporal_store(vfloat4{a1.x, a1.y, a1.z, a1.w}, &orow[lane + 64]);
    }
}

extern "C" void kernel_launch(void* const* d_in, const int* in_sizes, int n_in,
                              void* d_out, int out_size, void* d_ws, size_t ws_size,
                              hipStream_t stream) {
    const float* x      = (const float*)d_in[0];   // [8, 2048, 512] f32
    const float* points = (const float*)d_in[1];   // [8, 2048, 3]   f32
    float* out          = (float*)d_out;           // [8, 2048, 512] f32

    pointnetpp_knn_maxpool<<<dim3(BATCHES * (NPTS / (WAVES * QPW))),
                             dim3(512), 0, stream>>>(x, points, out);
}